// Round 1
// baseline (55.201 us; speedup 1.0000x reference)
//
#include <hip/hip_runtime.h>

// DeformationPerturbationLayer: dense [B,N,N] tent-weight einsum == bilinear
// interpolation with an analytic "localized bulge" displacement field:
//   dxc = 31.5 - x, dyc = 31.5 - y, g = exp(-(dxc^2+dyc^2)/512)
//   src_x = x + w[b]*dxc*g, src_y = y + w[b]*dyc*g
// out[b,c,y,x] = bilinear(image[c], src_y, src_x), zero padding outside.
//
// v2: 4 pixels per thread along x, float4 stores (3 stores/thread instead of
// 3 scalar stores/pixel). 8192 threads = 128 blocks x 64 (1 wave/block,
// spread across CUs). Each wave writes 1 KiB contiguous per channel.

#define H 64
#define W 64
#define C 3
#define B 8
#define N (H * W)

__global__ __launch_bounds__(64) void deform_bilinear_v4(
    const float* __restrict__ w,      // [B]
    const float* __restrict__ img,    // [C, H, W]
    float* __restrict__ out)          // [B, C, H, W]
{
    int tid = blockIdx.x * blockDim.x + threadIdx.x;  // 0 .. 8191
    int b  = tid >> 10;          // N/4 = 1024 quads per batch
    int q  = tid & 1023;
    int y  = q >> 4;             // 16 quads per row
    int x4 = (q & 15) << 2;      // first x of this thread's quad

    const float wb = w[b];
    const float dyc = 31.5f - (float)y;
    const float vy = dyc * dyc;
    const float inv2s2 = 1.0f / 512.0f;

    float o[C][4];

#pragma unroll
    for (int k = 0; k < 4; ++k) {
        int x = x4 + k;
        float dxc = 31.5f - (float)x;
        float g = expf(-(dxc * dxc + vy) * inv2s2);
        float sx = (float)x + wb * dxc * g;
        float sy = (float)y + wb * dyc * g;

        float fx0 = floorf(sx);
        float fy0 = floorf(sy);
        int x0 = (int)fx0;
        int y0 = (int)fy0;
        float ax = sx - fx0;
        float ay = sy - fy0;

        // per-tap weights, zeroed when the tap falls outside the grid
        float wx0 = (x0 >= 0 && x0 < W) ? (1.0f - ax) : 0.0f;
        float wx1 = (x0 + 1 >= 0 && x0 + 1 < W) ? ax : 0.0f;
        float wy0 = (y0 >= 0 && y0 < H) ? (1.0f - ay) : 0.0f;
        float wy1 = (y0 + 1 >= 0 && y0 + 1 < H) ? ay : 0.0f;

        // clamped indices so loads are always in-bounds (weight 0 if clamped)
        int x0c = min(max(x0, 0), W - 1);
        int x1c = min(max(x0 + 1, 0), W - 1);
        int y0c = min(max(y0, 0), H - 1);
        int y1c = min(max(y0 + 1, 0), H - 1);

        int i00 = (y0c << 6) + x0c;
        int i01 = (y0c << 6) + x1c;
        int i10 = (y1c << 6) + x0c;
        int i11 = (y1c << 6) + x1c;

        float w00 = wy0 * wx0;
        float w01 = wy0 * wx1;
        float w10 = wy1 * wx0;
        float w11 = wy1 * wx1;

#pragma unroll
        for (int c = 0; c < C; ++c) {
            const float* ic = img + (c << 12);
            o[c][k] = w00 * ic[i00] + w01 * ic[i01]
                    + w10 * ic[i10] + w11 * ic[i11];
        }
    }

    int n = (y << 6) + x4;
#pragma unroll
    for (int c = 0; c < C; ++c) {
        float4 v = make_float4(o[c][0], o[c][1], o[c][2], o[c][3]);
        *reinterpret_cast<float4*>(out + ((b * C + c) << 12) + n) = v;
    }
}

extern "C" void kernel_launch(void* const* d_in, const int* in_sizes, int n_in,
                              void* d_out, int out_size, void* d_ws, size_t ws_size,
                              hipStream_t stream) {
    const float* w   = (const float*)d_in[0];   // [8,1]
    const float* img = (const float*)d_in[1];   // [3,64,64]
    float* out = (float*)d_out;                 // [8,3,64,64]

    int total = (B * N) / 4;   // one thread per 4 output pixels: 8192
    int block = 64;            // 1 wave per block -> 128 blocks spread over CUs
    int grid = total / block;  // 128
    deform_bilinear_v4<<<grid, block, 0, stream>>>(w, img, out);
}